// Round 1
// baseline (696.968 us; speedup 1.0000x reference)
//
#include <hip/hip_runtime.h>
#include <math.h>

// (B, F, T, K) = (4096, 2048, 16, 8)
// logits[b,t,k] = sum_f h[b,f,t] * W[k,t,f] + bias[k,t]; out = sigmoid(logits), [B,T,K]
#define B_TOT 4096
#define F_DIM 2048
#define T_DIM 16
#define K_DIM 8
#define NB    4            // batches per workgroup
#define SF    64           // f-columns of W per tile
#define NSUP  (F_DIM / SF) // 32 tiles

// Direct global->LDS DMA, 16B per lane. LDS dest must be wave-uniform base + lane*16.
__device__ __forceinline__ void gload_lds16(const float* g, float* l) {
    __builtin_amdgcn_global_load_lds(
        (const __attribute__((address_space(1))) void*)g,
        (__attribute__((address_space(3))) void*)l,
        16, 0, 0);
}

__global__ __launch_bounds__(256)
void ta_kernel(const float* __restrict__ h, const float* __restrict__ W,
               const float* __restrict__ bias, float* __restrict__ out)
{
    // 32 KB: W tile (8k x 16t x 64f, float4-swizzled). Reused by the epilogue.
    __shared__ float smem[8192];

    const int tid = threadIdx.x;
    const int tp  = tid & 7;       // t-pair index: thread covers t = 2*tp + ts, ts in {0,1}
    const int fr  = tid >> 3;      // f residue 0..31 (f_local = il*32 + fr, il in {0,1})
    const int b0  = blockIdx.x * NB;

    float acc[NB][2][K_DIM];
#pragma unroll
    for (int nb = 0; nb < NB; ++nb)
#pragma unroll
        for (int ts = 0; ts < 2; ++ts)
#pragma unroll
            for (int k = 0; k < K_DIM; ++k) acc[nb][ts][k] = 0.f;

    // ---- W staging decode (global_load_lds), unchanged from proven kernel ----
    // smem[r*1024 + t*64 + u*4 + c] = W[r][t][sc*64 + ((u-t)&15)*4 + c]
    const int tl = tid >> 4;
    const int j4 = ((tid & 15) - tl) & 15;
    const float* wp = W + tl * F_DIM + j4 * 4;   // + r*32768 + sc*64 per load
    float* lp = smem + tid * 4;                  // + r*1024 per round

    // ---- ds_read word offsets: want W[k][t][sc*64 + il*32 + fr] ----
    // word w = il*8 + (fr>>2), byte-elem c = fr&3, u = (w + t)&15
    // bank = ((w+t)&7)*4 + (fr&3): 2-way max per quarter-wave (free).
    int voff[2][2];
#pragma unroll
    for (int il = 0; il < 2; ++il)
#pragma unroll
        for (int ts = 0; ts < 2; ++ts) {
            const int t = 2 * tp + ts;
            voff[il][ts] = t * 64 + ((il * 8 + (fr >> 2) + t) & 15) * 4 + (fr & 3);
        }

    // h as float2: elem2 index = b*16384 + sc*512 + il*256 + fr*8 + tp
    // wave lanes (fr,tp) -> contiguous 512B per load instruction.
    const float2* hb = (const float2*)h + (size_t)b0 * 16384 + fr * 8 + tp;

    float2 hA[2][NB], hB[2][NB];   // register double-buffer for h

    auto loadh = [&](float2 (&buf)[2][NB], int sc) {
#pragma unroll
        for (int il = 0; il < 2; ++il)
#pragma unroll
            for (int nb = 0; nb < NB; ++nb)
                buf[il][nb] = hb[(size_t)nb * 16384 + sc * 512 + il * 256];
    };

    auto tile = [&](int sc, float2 (&cur)[2][NB], float2 (&nxt)[2][NB],
                    bool pf, int scn) {
        __syncthreads();           // all waves done reading previous tile; drains prefetch
        {
            const float* wpf = wp + sc * SF;
#pragma unroll
            for (int r = 0; r < K_DIM; ++r)
                gload_lds16(wpf + r * (T_DIM * F_DIM), lp + r * 1024);
        }
        __syncthreads();           // W tile complete + visible
        if (pf) loadh(nxt, scn);   // issue next h prefetch: latency hides under FMAs below

#pragma unroll
        for (int il = 0; il < 2; ++il)
#pragma unroll
            for (int ts = 0; ts < 2; ++ts) {
                float wv[K_DIM];
#pragma unroll
                for (int k = 0; k < K_DIM; ++k)
                    wv[k] = smem[k * 1024 + voff[il][ts]];
#pragma unroll
                for (int nb = 0; nb < NB; ++nb) {
                    const float hx = ts ? cur[il][nb].y : cur[il][nb].x;
#pragma unroll
                    for (int k = 0; k < K_DIM; ++k)
                        acc[nb][ts][k] = fmaf(hx, wv[k], acc[nb][ts][k]);
                }
            }
    };

    loadh(hA, 0);
    for (int sc = 0; sc < NSUP; sc += 2) {      // NSUP even: named-buffer ping-pong, no runtime idx
        tile(sc,     hA, hB, true,          sc + 1);
        tile(sc + 1, hB, hA, sc + 2 < NSUP, sc + 2);
    }

    // ---- epilogue: reduce 32 fr-partials per (nb,t,k); two 32KB chunks ----
    // write slot: row = nbl*16 + t (256 floats), stripe kk*32, col = (fr + 4*tp)&31
    // writer banks: (fr + 4*tp)&31 distinct per quarter-wave -> conflict-free
    // reader banks: col = (tid+j)&31 distinct per quarter-wave -> conflict-free
#pragma unroll
    for (int c = 0; c < 2; ++c) {
        __syncthreads();           // smem free (last W tile / previous chunk fully read)
#pragma unroll
        for (int nbl = 0; nbl < 2; ++nbl)
#pragma unroll
            for (int ts = 0; ts < 2; ++ts) {
                const int t = 2 * tp + ts;
#pragma unroll
                for (int k = 0; k < K_DIM; ++k)
                    smem[(nbl * 16 + t) * 256 + k * 32 + ((fr + tp * 4) & 31)]
                        = acc[c * 2 + nbl][ts][k];
            }
        __syncthreads();
        const int nbl = tid >> 7, rem = tid & 127, tt = rem >> 3, kk = rem & 7;
        float s = 0.f;
#pragma unroll
        for (int j = 0; j < 32; ++j)
            s += smem[(nbl * 16 + tt) * 256 + kk * 32 + ((tid + j) & 31)];
        s += bias[kk * T_DIM + tt];
        s = 1.0f / (1.0f + __expf(-s));
        out[(size_t)(b0 + c * 2 + nbl) * (T_DIM * K_DIM) + rem] = s;
    }
}

extern "C" void kernel_launch(void* const* d_in, const int* in_sizes, int n_in,
                              void* d_out, int out_size, void* d_ws, size_t ws_size,
                              hipStream_t stream) {
    const float* h    = (const float*)d_in[0];   // [B, F, T] fp32
    const float* W    = (const float*)d_in[1];   // [K, T, F] fp32
    const float* bias = (const float*)d_in[2];   // [K, T] fp32
    float* out = (float*)d_out;                  // [B, T, K] fp32
    ta_kernel<<<dim3(B_TOT / NB), dim3(256), 0, stream>>>(h, W, bias, out);
}